// Round 7
// baseline (249.418 us; speedup 1.0000x reference)
//
#include <hip/hip_runtime.h>

// RandomlyLocalizedConformalRiskControl on MI355X.
// ws layout (bytes), total ~98.5 MB (non-overlapping; round-6 crash was cdf/grouped overlap):
//   test_res f32 [32][65536]             @ 0          (8 MB)    f32 scores for k_finalp
//   cal_bf   u16 [256][65536]            @ 8388608    (32 MB)   bf16 cal scores (MFMA A/B)
//   test_bf  u16 [32][65536]             @ 41943040   (4 MB)    bf16 test scores
//   grouped  u16 [256][65536]            @ 46137344   (32 MB)   ends 79691776
//   cdf      u32 [256][CDF_STRIDE]       @ 79691776   (16.7 MB) ends 96354304
//   gpart    f32 [64][8][1024]           @ 96354304   (2 MB)    ends 98451456
//   cc f32[256] @98451456, thr f32[32] @98452480, lam f32[32] @98452608, facc i32[32][4] @98452736

#define NPIX 65536
#define HB 16256            // buckets = float_bits >> 16 for scores in (0, 1.0]
#define CDF_STRIDE 16272
#define ALPHA 0.1f

#define OFF_TESTRES  0
#define OFF_CALBF    8388608u
#define OFF_TESTBF   41943040u
#define OFF_GROUPED  46137344u
#define OFF_CDF      79691776u
#define OFF_GPART    96354304u
#define OFF_CC       98451456u
#define OFF_THR      98452480u
#define OFF_LAM      98452608u
#define OFF_FACC     98452736u

typedef __attribute__((ext_vector_type(8))) short bf16x8;
typedef __attribute__((ext_vector_type(16))) float f32x16;

__device__ __forceinline__ unsigned short f2bf_rne(float f) {
  unsigned u = __float_as_uint(f);
  return (unsigned short)((u + 0x7FFFu + ((u >> 16) & 1u)) >> 16);
}

// Shared by phase A / phase B / cal / test: identical inlined expression tree
// -> identical FMA contraction -> bit-identical f32 result on recompute.
// Works for both LDS and global src pointers.
__device__ __forceinline__ float score_at(const float* __restrict__ src,
                                          int x0, int x1, float wx, int y) {
  float sy = 0.25f * (float)y - 0.375f;
  int y0 = (int)floorf(sy);
  float wy = sy - (float)y0;
  int y1 = y0 + 1;
  if (y0 < 0) y0 = 0;
  if (y1 > 63) y1 = 63;
  float a = src[y0 * 64 + x0] * (1.f - wx) + src[y0 * 64 + x1] * wx;
  float b = src[y1 * 64 + x0] * (1.f - wx) + src[y1 * 64 + x1] * wx;
  float v = a * (1.f - wy) + b * wy;
  return 1.f / (1.f + __expf(-v));
}

// ---- cal: features + histogram + CDF + counting scatter + cc, then 1/256 of test scoring ----
// Grid = exactly 256 blocks (1/CU): no dispatch tail; test work spread uniformly.
__global__ __launch_bounds__(1024, 4) void k_cal(const float* __restrict__ featc,
                                                 const int* __restrict__ gt,
                                                 unsigned short* __restrict__ calbf,
                                                 unsigned* __restrict__ cdf,
                                                 unsigned short* __restrict__ grouped,
                                                 float* __restrict__ cc,
                                                 const float* __restrict__ featt,
                                                 float* __restrict__ tres,
                                                 unsigned short* __restrict__ tbf) {
  __shared__ unsigned smem[16384];  // [0,HB): hist -> exclusive scan -> scatter counters
  __shared__ float sfeat[4096];
  const int n = blockIdx.x, tid = threadIdx.x;
  const int lane = tid & 63, wv = tid >> 6;
  const int x = tid & 255, yq = tid >> 8;  // yq in 0..3
  for (int i = tid; i < 16320; i += 1024) smem[i] = 0;
  for (int i = tid; i < 4096; i += 1024) sfeat[i] = featc[n * 4096 + i];
  const int* gtn = gt + (size_t)n * NPIX;
  unsigned short* cbn = calbf + (size_t)n * NPIX;
  float sx = 0.25f * (float)x - 0.375f;
  int x0 = (int)floorf(sx);
  float wx = sx - (float)x0;
  int x1 = x0 + 1;
  if (x0 < 0) x0 = 0;
  if (x1 > 63) x1 = 63;
  __syncthreads();  // S0
  unsigned long long pm = 0ull;
  float sumsq = 0.f;
  #pragma unroll 8
  for (int it = 0; it < 64; ++it) {
    int y = it * 4 + yq;
    float s = score_at(sfeat, x0, x1, wx, y);
    int p = (y << 8) + x;
    unsigned short bh = f2bf_rne(s);
    cbn[p] = bh;
    float sr = __uint_as_float((unsigned)bh << 16);
    sumsq += sr * sr;
    if (gtn[p] > 0) {
      pm |= (1ull << it);
      atomicAdd(&smem[__float_as_uint(s) >> 16], 1u);
    }
  }
  // cc partials (16 waves)
  #pragma unroll
  for (int off = 32; off; off >>= 1) sumsq += __shfl_xor(sumsq, off);
  if (lane == 0) smem[16336 + wv] = __float_as_uint(sumsq);
  __syncthreads();  // S1: hist + cc partials final
  if (tid == 0) {
    float c = 0.f;
    for (int w = 0; w < 16; ++w) c += __uint_as_float(smem[16336 + w]);
    cc[n] = c;
  }
  // exclusive scan of 16256 buckets on threads 0..255 (64/thread), wave shfl scan of partials
  unsigned* cdfn = cdf + (size_t)n * CDF_STRIDE;
  if (tid < 256) {
    const int base = tid * 64;
    unsigned psum = 0;
    if (base < HB) {
      for (int j = 0; j < 64; ++j) psum += smem[base + ((j + tid) & 63)];  // rotated: conflict-free
    }
    unsigned inc = psum;
    #pragma unroll
    for (int off = 1; off < 64; off <<= 1) {
      unsigned v = __shfl_up(inc, off);
      if (lane >= off) inc += v;
    }
    if (lane == 63) smem[16320 + wv] = inc;
  }
  __syncthreads();  // S2
  if (tid < 256) {
    const int base = tid * 64;
    unsigned psum = 0;
    if (base < HB) {
      for (int j = 0; j < 64; ++j) psum += smem[base + ((j + tid) & 63)];
    }
    unsigned inc = psum;
    #pragma unroll
    for (int off = 1; off < 64; off <<= 1) {
      unsigned v = __shfl_up(inc, off);
      if (lane >= off) inc += v;
    }
    unsigned woff = 0;
    for (int w = 0; w < wv; ++w) woff += smem[16320 + w];
    unsigned run = woff + inc - psum;
    if (base < HB) {
      for (int j = 0; j < 64; ++j) {  // in-place exclusive scan (own chunk: no race)
        unsigned h = smem[base + j];
        smem[base + j] = run;
        run += h;
      }
    }
    if (tid == 255) cdfn[HB] = woff + inc;  // total positives
  }
  __syncthreads();  // S3: smem = exclusive scan (scatter counters)
  for (int i = tid; i < HB; i += 1024) cdfn[i] = smem[i];  // coalesced CDF dump
  __syncthreads();  // S4: dump done before scatter mutates counters
  // phase B: recompute scores (bit-exact via shared score_at) for positives, counting scatter
  unsigned short* gn = grouped + (size_t)n * NPIX;
  for (int it = 0; it < 64; ++it) {
    if (pm & (1ull << it)) {
      int y = it * 4 + yq;
      float s = score_at(sfeat, x0, x1, wx, y);
      unsigned bits = __float_as_uint(s);
      unsigned idx = atomicAdd(&smem[bits >> 16], 1u);
      gn[idx] = (unsigned short)(bits & 0xFFFFu);
    }
  }
  // test slab: block n -> test sample n>>3, y rows [(n&7)*32, +32); feat via L1/L2
  const int tb2 = n >> 3, ybase = (n & 7) * 32;
  const float* tfp = featt + tb2 * 4096;
  float* resb = tres + (size_t)tb2 * NPIX;
  unsigned short* tbn = tbf + (size_t)tb2 * NPIX;
  #pragma unroll
  for (int i = 0; i < 8; ++i) {
    int y = ybase + (i << 2) + yq;
    float s = score_at(tfp, x0, x1, wx, y);
    int p = (y << 8) + x;
    resb[p] = s;
    tbn[p] = f2bf_rne(s);
  }
}

// ---- LDS-staged bf16 MFMA GEMM: gpart[ks][nt][m*32+nl] = <test_m, cal_(nt*32+nl)> ----
__global__ __launch_bounds__(256) void k_gemm(const unsigned short* __restrict__ tbf,
                                              const unsigned short* __restrict__ cbf,
                                              float* __restrict__ gpart) {
  __shared__ __align__(16) unsigned short As[16384];  // 32 KB: 64 kblk x 32 row x 8 elems
  __shared__ __align__(16) unsigned short Bs[16384];
  __shared__ float lred[4][1024];                     // 16 KB
  const int tid = threadIdx.x;
  const int lane = tid & 63, wv = tid >> 6;
  const int r = lane & 31, half = lane >> 5;
  const int nt = blockIdx.x;              // 0..7: cal column tile
  f32x16 acc;
  #pragma unroll
  for (int i = 0; i < 16; ++i) acc[i] = 0.f;
  for (int ch = 0; ch < 2; ++ch) {        // two 512-K chunks of this block's 1024-K slice
    const size_t kbase = (size_t)blockIdx.y * 1024 + ch * 512;
    __syncthreads();
    #pragma unroll
    for (int s = 0; s < 16; ++s) {
      int flat = s * 256 + tid;           // 0..4095; <2048 = A, else B (wave-uniform per s)
      int rem = flat & 2047;
      int row = rem >> 6, kb = rem & 63;
      const unsigned short* src = (flat >= 2048)
          ? cbf + (size_t)(nt * 32 + row) * NPIX + kbase + kb * 8
          : tbf + (size_t)row * NPIX + kbase + kb * 8;
      int slot = ((kb << 5) + row) ^ (kb & 31);   // XOR swizzle breaks write-bank collisions
      int4 v = *(const int4*)src;
      *(int4*)((flat >= 2048 ? Bs : As) + slot * 8) = v;
    }
    __syncthreads();
    #pragma unroll
    for (int i = 0; i < 8; ++i) {         // wave's K-quarter: kblk in [wv*16, wv*16+16)
      int k8 = (wv << 4) + i * 2 + half;
      int slot = ((k8 << 5) + r) ^ (k8 & 31);
      bf16x8 a = *(const bf16x8*)(As + slot * 8);
      bf16x8 b = *(const bf16x8*)(Bs + slot * 8);
      acc = __builtin_amdgcn_mfma_f32_32x32x16_bf16(a, b, acc, 0, 0, 0);
    }
  }
  // C/D layout (HW-verified): col = lane&31, row = (reg&3) + 8*(reg>>2) + 4*(lane>>5)
  #pragma unroll
  for (int rg = 0; rg < 16; ++rg) {
    int m = (rg & 3) + 8 * (rg >> 2) + 4 * half;
    lred[wv][m * 32 + r] = acc[rg];
  }
  __syncthreads();
  float* gp = gpart + (size_t)(blockIdx.y * 8 + nt) * 1024;
  for (int e = tid; e < 1024; e += 256)
    gp[e] = lred[0][e] + lred[1][e] + lred[2][e] + lred[3][e];
}

// ---- tt + weights + direct weighted-quantile; zero-inits facc ----
__global__ __launch_bounds__(512) void k_quant(const float* __restrict__ gpart,
                                               const float* __restrict__ cc,
                                               const unsigned* __restrict__ cdf,
                                               const unsigned short* __restrict__ grouped,
                                               const unsigned short* __restrict__ tbf,
                                               float* __restrict__ lam,
                                               float* __restrict__ thr,
                                               int* __restrict__ facc) {
  __shared__ float qs[256];
  __shared__ float bins[4096];
  __shared__ float red[8];
  __shared__ float bc[4];      // [0]=tt, [1]=wsum, [2]=S(mid)
  __shared__ unsigned sBin;
  const int b = blockIdx.x, tid = threadIdx.x;
  const int lane = tid & 63, wv = tid >> 6;

  if (tid < 4) facc[b * 4 + tid] = 0;
  for (int i = tid; i < 4096; i += 512) bins[i] = 0.f;
  if (tid == 0) sBin = 0xFFFFFFFFu;

  // ---- tt[b] = sum of (bf16 test score)^2 over row b ----
  float ts = 0.f;
  const int4* tbp = (const int4*)(tbf + (size_t)b * NPIX);
  for (int i = tid; i < 8192; i += 512) {
    int4 v = tbp[i];
    unsigned w0 = (unsigned)v.x, w1 = (unsigned)v.y, w2 = (unsigned)v.z, w3 = (unsigned)v.w;
    float f;
    f = __uint_as_float(w0 << 16); ts += f * f;
    f = __uint_as_float(w0 & 0xFFFF0000u); ts += f * f;
    f = __uint_as_float(w1 << 16); ts += f * f;
    f = __uint_as_float(w1 & 0xFFFF0000u); ts += f * f;
    f = __uint_as_float(w2 << 16); ts += f * f;
    f = __uint_as_float(w2 & 0xFFFF0000u); ts += f * f;
    f = __uint_as_float(w3 << 16); ts += f * f;
    f = __uint_as_float(w3 & 0xFFFF0000u); ts += f * f;
  }
  #pragma unroll
  for (int off = 32; off; off >>= 1) ts += __shfl_xor(ts, off);
  if (lane == 0) red[wv] = ts;
  __syncthreads();
  if (tid == 0) {
    float t = 0.f;
    for (int w = 0; w < 8; ++w) t += red[w];
    bc[0] = t;
  }
  __syncthreads();
  const float ttv = bc[0];

  // ---- weights: k_n = exp(-d2/8192), d2 = tt + cc - 2*sum_ks gpart ----
  float k = 0.f;
  if (tid < 256) {
    const float* gp = gpart + ((tid >> 5) * 1024) + (b * 32) + (tid & 31);
    float g = 0.f;
    #pragma unroll 8
    for (int ks = 0; ks < 64; ++ks) g += gp[(size_t)ks * 8192];
    float d2 = ttv + cc[tid] - 2.f * g;
    k = expf(-d2 * (1.f / 8192.f));
  }
  float v = k;
  #pragma unroll
  for (int off = 32; off; off >>= 1) v += __shfl_xor(v, off);
  if (lane == 0) red[wv] = v;
  __syncthreads();
  if (tid == 0) {
    float ws = 1.f;
    for (int w = 0; w < 8; ++w) ws += red[w];
    bc[1] = ws;
  }
  __syncthreads();
  const float wsum = bc[1];
  const float wlast = 1.f / wsum;
  const float R = ALPHA - wlast;
  if (R <= 0.f) {  // risk >= alpha for every lam -> low -> 1.0f, thr 0 (predict all)
    if (tid == 0) { lam[b] = 1.0f; thr[b] = 0.0f; }
    return;
  }
  if (tid < 256) {
    unsigned pos = cdf[(size_t)tid * CDF_STRIDE + HB];
    qs[tid] = k / (wsum * (float)(pos ? pos : 1u));
  }
  __syncthreads();

  // ---- 14-step binary search over hi-16 buckets: invariant S(lo) < R <= S(hi) ----
  int lo = 0, hi = HB;
  float baseS = 0.f;
  for (int it = 0; it < 14; ++it) {
    int mid = (lo + hi) >> 1;
    float p = 0.f;
    if (tid < 256) p = qs[tid] * (float)cdf[(size_t)tid * CDF_STRIDE + mid];
    float r = p;
    #pragma unroll
    for (int off = 32; off; off >>= 1) r += __shfl_xor(r, off);
    if (lane == 0) red[wv] = r;
    __syncthreads();
    if (tid == 0) {
      float s = 0.f;
      for (int w = 0; w < 8; ++w) s += red[w];
      bc[2] = s;
    }
    __syncthreads();
    float S = bc[2];
    if (S < R) { lo = mid; baseS = S; } else { hi = mid; }
  }
  const int B = lo;  // crossing bucket; baseS = weighted count below it

  // ---- gather bucket B members into 4096-bin weighted histogram of lo16>>4 ----
  {
    const int n = tid >> 1;
    const float q = qs[n];
    const unsigned* cn = cdf + (size_t)n * CDF_STRIDE;
    const unsigned short* gn = grouped + (size_t)n * NPIX;
    unsigned e0 = cn[B + 1];
    for (unsigned j = cn[B] + (tid & 1); j < e0; j += 2)
      atomicAdd(&bins[gn[j] >> 4], q);
  }
  __syncthreads();

  // ---- wave 0: scan 4096 bins, find crossing bin ----
  if (wv == 0) {
    float s = 0.f;
    for (int j = 0; j < 64; ++j) s += bins[lane * 64 + j];
    float inc = s;
    #pragma unroll
    for (int off = 1; off < 64; off <<= 1) {
      float u = __shfl_up(inc, off);
      if (lane >= off) inc += u;
    }
    float pre = inc - s;
    bool hit = (baseS + pre < R) && (baseS + inc >= R);
    unsigned long long m = __ballot(hit);
    int ow = m ? (__ffsll((unsigned long long)m) - 1) : -1;
    if (lane == ow) {
      float run = baseS + pre;
      unsigned bin = (unsigned)lane * 64 + 63;
      for (int j = 0; j < 64; ++j) {
        float bv = bins[lane * 64 + j];
        if (run + bv >= R) { bin = (unsigned)lane * 64 + j; break; }
        run += bv;
      }
      sBin = bin;
    }
    if (m == 0 && lane == 0) sBin = 4095u;  // f32-rounding fallback (unreachable in practice)
  }
  __syncthreads();
  if (tid == 0) {
    unsigned tb = ((unsigned)B << 16) | (sBin << 4);
    lam[b] = 1.0f - __uint_as_float(tb | 0x8u);     // mid-bin representative
    thr[b] = __uint_as_float((tb | 0xFu) + 1u);     // strictly above bin top: pred = res > u*
  }
}

// ---- final partials: grid (32 samples, 8 segments), atomic int accumulate ----
__global__ __launch_bounds__(256) void k_finalp(const float* __restrict__ tres,
                                                const int* __restrict__ tgt,
                                                const float* __restrict__ thr,
                                                int* __restrict__ facc) {
  __shared__ int red[12];
  const int b = blockIdx.x, seg = blockIdx.y, tid = threadIdx.x;
  const int lane = tid & 63, wv = tid >> 6;
  const float th = thr[b];
  const float* rb = tres + (size_t)b * NPIX + seg * 8192;
  const int* gb = tgt + (size_t)b * NPIX + seg * 8192;
  int sz = 0, tp = 0, tpos = 0;
  for (int i = 0; i < 32; ++i) {
    int p = i * 256 + tid;
    int pred = (rb[p] >= th) ? 1 : 0;
    int tg = (gb[p] > 0) ? 1 : 0;
    sz += pred;
    tp += pred & tg;
    tpos += tg;
  }
  #pragma unroll
  for (int off = 32; off; off >>= 1) {
    sz += __shfl_xor(sz, off);
    tp += __shfl_xor(tp, off);
    tpos += __shfl_xor(tpos, off);
  }
  if (lane == 0) { red[wv] = sz; red[4 + wv] = tp; red[8 + wv] = tpos; }
  __syncthreads();
  if (tid == 0) {
    int s0 = red[0] + red[1] + red[2] + red[3];
    int s1 = red[4] + red[5] + red[6] + red[7];
    int s2 = red[8] + red[9] + red[10] + red[11];
    atomicAdd(&facc[b * 4 + 0], s0);
    atomicAdd(&facc[b * 4 + 1], s1);
    atomicAdd(&facc[b * 4 + 2], s2);
  }
}

// ---- emit outputs ----
__global__ void k_out(const int* __restrict__ facc, const float* __restrict__ lam,
                      float* __restrict__ out) {
  int b = threadIdx.x;
  if (b < 32) {
    int sz = facc[b * 4], tp = facc[b * 4 + 1], tpos = facc[b * 4 + 2];
    float tposf = (float)(tpos > 0 ? tpos : 1);
    out[b] = 1.f - (float)tp / tposf;   // fnr_test
    out[32 + b] = lam[b];               // lambda
    out[64 + b] = (float)sz;            // size
  }
}

extern "C" void kernel_launch(void* const* d_in, const int* in_sizes, int n_in,
                              void* d_out, int out_size, void* d_ws, size_t ws_size,
                              hipStream_t stream) {
  const float* cal_feat = (const float*)d_in[0];
  const float* test_feat = (const float*)d_in[1];
  const int* cal_gt = (const int*)d_in[2];
  const int* test_gt = (const int*)d_in[3];
  float* out = (float*)d_out;
  char* ws = (char*)d_ws;

  float* test_res = (float*)(ws + OFF_TESTRES);
  unsigned short* cal_bf = (unsigned short*)(ws + OFF_CALBF);
  unsigned short* test_bf = (unsigned short*)(ws + OFF_TESTBF);
  unsigned short* grouped = (unsigned short*)(ws + OFF_GROUPED);
  unsigned* cdf = (unsigned*)(ws + OFF_CDF);
  float* gpart = (float*)(ws + OFF_GPART);
  float* cc = (float*)(ws + OFF_CC);
  float* thr = (float*)(ws + OFF_THR);
  float* lam = (float*)(ws + OFF_LAM);
  int* facc = (int*)(ws + OFF_FACC);

  k_cal<<<dim3(256), dim3(1024), 0, stream>>>(cal_feat, cal_gt, cal_bf, cdf, grouped, cc,
                                              test_feat, test_res, test_bf);
  k_gemm<<<dim3(8, 64), dim3(256), 0, stream>>>(test_bf, cal_bf, gpart);
  k_quant<<<dim3(32), dim3(512), 0, stream>>>(gpart, cc, cdf, grouped, test_bf, lam, thr, facc);
  k_finalp<<<dim3(32, 8), dim3(256), 0, stream>>>(test_res, test_gt, thr, facc);
  k_out<<<dim3(1), dim3(64), 0, stream>>>(facc, lam, out);
}